// Round 7
// baseline (138.740 us; speedup 1.0000x reference)
//
#include <hip/hip_runtime.h>
#include <math.h>

#define N_NODES 1024
#define T_STEPS 36
#define KTILE   128          // k-nodes per attn V tile
#define VTSTR   136          // V^T LDS row stride (bf16): 128 data + 8 pad
#define WOS     72           // outproj Wo LDS stride (bf16)
#define OBS2    72           // outproj ob-tile LDS stride (bf16)
#define YSTR6   17           // proj6 V-transpose LDS row stride (uint32)

typedef __bf16  bf16x8 __attribute__((ext_vector_type(8)));
typedef float   f32x4  __attribute__((ext_vector_type(4)));

#define MFMA_BF16 __builtin_amdgcn_mfma_f32_16x16x32_bf16
#define PERM_HI 0x07060302u   // (a,b) -> hi16(b) | hi16(a)<<16
#define PERM_LO 0x05040100u   // (a,b) -> lo16(b) | lo16(a)<<16

__device__ __forceinline__ unsigned short bf16_rne(float f) {
    unsigned int u = __float_as_uint(f);
    u += 0x7FFFu + ((u >> 16) & 1u);
    return (unsigned short)(u >> 16);
}
__device__ __forceinline__ float bf16_tof(unsigned short h) {
    return __uint_as_float(((unsigned int)h) << 16);
}

// ---------------------------------------------------------------------------
// Kernel 1 (proj6): coalesced-read projection; Q/K stored straight from
// registers (per-thread 32B runs -> dense 1KB wave segments); only V takes
// the LDS transpose (per-hd, 8.7KB). Per-hd x-loading keeps VGPR ~50.
// Block = 128 thr = (64 n) x (2 t); blockIdx.y: 0=v, 1=k, 2=q.
// ---------------------------------------------------------------------------
__global__ __launch_bounds__(128) void proj6_kernel(
    const float* __restrict__ vin, const float* __restrict__ kin, const float* __restrict__ qin,
    const float* __restrict__ Wv, const float* __restrict__ Wk, const float* __restrict__ Wq,
    unsigned short* __restrict__ qhi, unsigned short* __restrict__ qlo,
    unsigned short* __restrict__ khi, unsigned short* __restrict__ klo,
    unsigned short* __restrict__ vthi, unsigned short* __restrict__ vtlo)
{
    __shared__ float sW[256];
    __shared__ unsigned int ys[128 * YSTR6];   // V only: [row(nl*2+tl)][e] hi|lo

    const int tid = threadIdx.x;
    const int mat = blockIdx.y;               // 0=v, 1=k, 2=q
    const int nt  = blockIdx.x & 15;
    const int tt  = blockIdx.x >> 4;          // 0..17
    const int n0  = nt * 64, t0 = tt * 2;

    const float* in = (mat == 0) ? vin : (mat == 1) ? kin : qin;
    const float* W  = (mat == 0) ? Wv  : (mat == 1) ? Wk  : Wq;
    sW[tid] = W[tid]; sW[tid + 128] = W[tid + 128];
    __syncthreads();

    const int nl = tid >> 1, tl = tid & 1;
    const int n = n0 + nl, tcur = t0 + tl;
    const size_t ib = ((size_t)n * T_STEPS + tcur) * 64;
    const float scale = (mat == 2) ? 0.18033688011112042f : 1.0f;  // log2(e)/8 on Q

    if (mat != 0) {
        unsigned short* ohi = (mat == 1) ? khi : qhi;
        unsigned short* olo = (mat == 1) ? klo : qlo;
        #pragma unroll
        for (int hd = 0; hd < 4; ++hd) {
            float xr[16];
            #pragma unroll
            for (int i = 0; i < 4; ++i) {
                float4 f = *(const float4*)(in + ib + hd*16 + 4*i);
                xr[4*i] = f.x; xr[4*i+1] = f.y; xr[4*i+2] = f.z; xr[4*i+3] = f.w;
            }
            union { unsigned short u[16]; uint4 v[2]; } hb, lb;
            #pragma unroll
            for (int e = 0; e < 16; ++e) {
                float4 w0 = *(const float4*)&sW[e*16+0],  w1 = *(const float4*)&sW[e*16+4];
                float4 w2 = *(const float4*)&sW[e*16+8],  w3 = *(const float4*)&sW[e*16+12];
                float a = xr[0]*w0.x;
                a = fmaf(xr[1],w0.y,a);  a = fmaf(xr[2],w0.z,a);  a = fmaf(xr[3],w0.w,a);
                a = fmaf(xr[4],w1.x,a);  a = fmaf(xr[5],w1.y,a);  a = fmaf(xr[6],w1.z,a);  a = fmaf(xr[7],w1.w,a);
                a = fmaf(xr[8],w2.x,a);  a = fmaf(xr[9],w2.y,a);  a = fmaf(xr[10],w2.z,a); a = fmaf(xr[11],w2.w,a);
                a = fmaf(xr[12],w3.x,a); a = fmaf(xr[13],w3.y,a); a = fmaf(xr[14],w3.z,a); a = fmaf(xr[15],w3.w,a);
                a *= scale;
                unsigned short hh = bf16_rne(a);
                hb.u[e] = hh; lb.u[e] = bf16_rne(a - bf16_tof(hh));
            }
            const int th = tcur * 4 + hd;
            const size_t off = ((size_t)th * N_NODES + n) * 16;
            *(uint4*)(ohi + off)     = hb.v[0];
            *(uint4*)(ohi + off + 8) = hb.v[1];
            *(uint4*)(olo + off)     = lb.v[0];
            *(uint4*)(olo + off + 8) = lb.v[1];
        }
    } else {
        #pragma unroll
        for (int hd = 0; hd < 4; ++hd) {
            {   // phase A: project this hd, stage packed hi|lo in LDS
                float xr[16];
                #pragma unroll
                for (int i = 0; i < 4; ++i) {
                    float4 f = *(const float4*)(in + ib + hd*16 + 4*i);
                    xr[4*i] = f.x; xr[4*i+1] = f.y; xr[4*i+2] = f.z; xr[4*i+3] = f.w;
                }
                unsigned int* yrow = &ys[tid * YSTR6];
                #pragma unroll
                for (int e = 0; e < 16; ++e) {
                    float4 w0 = *(const float4*)&sW[e*16+0],  w1 = *(const float4*)&sW[e*16+4];
                    float4 w2 = *(const float4*)&sW[e*16+8],  w3 = *(const float4*)&sW[e*16+12];
                    float a = xr[0]*w0.x;
                    a = fmaf(xr[1],w0.y,a);  a = fmaf(xr[2],w0.z,a);  a = fmaf(xr[3],w0.w,a);
                    a = fmaf(xr[4],w1.x,a);  a = fmaf(xr[5],w1.y,a);  a = fmaf(xr[6],w1.z,a);  a = fmaf(xr[7],w1.w,a);
                    a = fmaf(xr[8],w2.x,a);  a = fmaf(xr[9],w2.y,a);  a = fmaf(xr[10],w2.z,a); a = fmaf(xr[11],w2.w,a);
                    a = fmaf(xr[12],w3.x,a); a = fmaf(xr[13],w3.y,a); a = fmaf(xr[14],w3.z,a); a = fmaf(xr[15],w3.w,a);
                    unsigned short hh = bf16_rne(a);
                    unsigned short ll = bf16_rne(a - bf16_tof(hh));
                    yrow[e] = ((unsigned int)hh << 16) | ll;
                }
            }
            __syncthreads();
            {   // phase B: transposed coalesced V store for this hd
                const int e = tid >> 3, ng = tid & 7;
                #pragma unroll
                for (int tl2 = 0; tl2 < 2; ++tl2) {
                    unsigned int u[8];
                    #pragma unroll
                    for (int j = 0; j < 8; ++j)
                        u[j] = ys[((ng*8 + j)*2 + tl2) * YSTR6 + e];
                    uint4 hi4, lo4;
                    hi4.x = __builtin_amdgcn_perm(u[1], u[0], PERM_HI);
                    hi4.y = __builtin_amdgcn_perm(u[3], u[2], PERM_HI);
                    hi4.z = __builtin_amdgcn_perm(u[5], u[4], PERM_HI);
                    hi4.w = __builtin_amdgcn_perm(u[7], u[6], PERM_HI);
                    lo4.x = __builtin_amdgcn_perm(u[1], u[0], PERM_LO);
                    lo4.y = __builtin_amdgcn_perm(u[3], u[2], PERM_LO);
                    lo4.z = __builtin_amdgcn_perm(u[5], u[4], PERM_LO);
                    lo4.w = __builtin_amdgcn_perm(u[7], u[6], PERM_LO);
                    const int th = (t0 + tl2) * 4 + hd;
                    const size_t off = ((size_t)th * 16 + e) * N_NODES + n0 + ng * 8;
                    *(uint4*)(vthi + off) = hi4;
                    *(uint4*)(vtlo + off) = lo4;
                }
            }
            if (hd < 3) __syncthreads();
        }
    }
}

// ---------------------------------------------------------------------------
// Kernel 2 (attn_mfma5): K direct from global (coalesced A-fragments, no K
// LDS); V staged via register-prefetch double-buffer (latency overlapped
// with compute). LDS 8.5KB; 128 thr, launch_bounds(128,5) -> all 9
// offered blocks/CU resident. lsum via ones-MFMA; fixed-shift softmax.
// ---------------------------------------------------------------------------
__global__ __launch_bounds__(128, 5) void attn_mfma5_kernel(
    const unsigned short* __restrict__ qhi, const unsigned short* __restrict__ qlo,
    const unsigned short* __restrict__ khi, const unsigned short* __restrict__ klo,
    const unsigned short* __restrict__ vthi, const unsigned short* __restrict__ vtlo,
    unsigned short* __restrict__ obh, unsigned short* __restrict__ obl)
{
    __shared__ unsigned short vthi_s[16 * VTSTR];   // permuted node order per 32-chunk
    __shared__ unsigned short vtlo_s[16 * VTSTR];

    const int tid  = threadIdx.x;
    const int wave = tid >> 6, lane = tid & 63;
    const int m = lane & 15, quad = lane >> 4;

    const int bid = blockIdx.x;
    const int th  = bid % 144;          // th mod 8 stable -> XCD-local K/V reuse
    const int qb  = bid / 144;
    const int t   = th >> 2, hd = th & 3;
    const int q0  = qb * 64;
    const size_t base_th = (size_t)th * N_NODES;

    // Q as B-operand, 2 rowgroups resident in registers.
    const bf16x8 bzero = {};
    bf16x8 b1q[2], b2q[2];
    #pragma unroll
    for (int g = 0; g < 2; ++g) {
        const int qrow = q0 + wave * 32 + g * 16 + m;
        b1q[g] = *(const bf16x8*)(qhi + (base_th + qrow) * 16 + (quad & 1) * 8);
        b2q[g] = (quad < 2)
            ? *(const bf16x8*)(qlo + (base_th + qrow) * 16 + (quad & 1) * 8) : bzero;
    }

    // all-ones B fragment for the l row-sum MFMA
    union { unsigned short su[8]; bf16x8 v; } onesu;
    #pragma unroll
    for (int i = 0; i < 8; ++i) onesu.su[i] = 0x3F80;
    const bf16x8 bones = onesu.v;

    f32x4 og[2]   = {{0.f,0.f,0.f,0.f},{0.f,0.f,0.f,0.f}};
    f32x4 lacc[2] = {{0.f,0.f,0.f,0.f},{0.f,0.f,0.f,0.f}};

    // K A-fragments direct from global: lane(m,quad) reads row j*16+m,
    // 16B half (quad&1) of plane (quad<2 ? hi : lo) -> dense 512B/quad-pair.
    const unsigned short* kfrag = ((quad < 2) ? khi : klo)
        + (base_th + m) * 16 + (quad & 1) * 8;

    // V staging: wave0 -> hi plane, wave1 -> lo plane; thread = (d, quarter)
    const int vd = (tid >> 2) & 15, vpart = tid & 3;
    const unsigned short* vsrc0 = (wave ? vtlo : vthi)
        + ((size_t)th * 16 + vd) * N_NODES + vpart * 32;
    unsigned short* vdst = (wave ? vtlo_s : vthi_s) + vd * VTSTR + vpart * 32;

    // prefetch V tile 0
    uint4 pf0, pf1, pf2, pf3;
    { const uint4* s = (const uint4*)vsrc0; pf0 = s[0]; pf1 = s[1]; pf2 = s[2]; pf3 = s[3]; }

    for (int kt = 0; kt < N_NODES; kt += KTILE) {
        __syncthreads();                 // previous tile's V readers done
        // write prefetched V, permuted: node n(0..31) -> pos ((n>>2)&3)*8+(n>>4)*4+(n&3)
        *(uint2*)&vdst[0]  = make_uint2(pf0.x, pf0.y);
        *(uint2*)&vdst[8]  = make_uint2(pf0.z, pf0.w);
        *(uint2*)&vdst[16] = make_uint2(pf1.x, pf1.y);
        *(uint2*)&vdst[24] = make_uint2(pf1.z, pf1.w);
        *(uint2*)&vdst[4]  = make_uint2(pf2.x, pf2.y);
        *(uint2*)&vdst[12] = make_uint2(pf2.z, pf2.w);
        *(uint2*)&vdst[20] = make_uint2(pf3.x, pf3.y);
        *(uint2*)&vdst[28] = make_uint2(pf3.z, pf3.w);
        __syncthreads();
        if (kt + KTILE < N_NODES) {      // prefetch next V tile (covers full tile)
            const uint4* s = (const uint4*)(vsrc0 + kt + KTILE);
            pf0 = s[0]; pf1 = s[1]; pf2 = s[2]; pf3 = s[3];
        }

        #pragma unroll
        for (int c = 0; c < 4; ++c) {    // 32-node group = S-tiles 2c, 2c+1
            bf16x8 a0 = *(const bf16x8*)(kfrag + (size_t)(kt + (2*c    )*16) * 16);
            bf16x8 a1 = *(const bf16x8*)(kfrag + (size_t)(kt + (2*c + 1)*16) * 16);
            bf16x8 vh = *(const bf16x8*)&vthi_s[m * VTSTR + quad * 8 + c * 32];
            bf16x8 vl = *(const bf16x8*)&vtlo_s[m * VTSTR + quad * 8 + c * 32];
            #pragma unroll
            for (int g = 0; g < 2; ++g) {
                f32x4 s0 = MFMA_BF16(a0, b1q[g], (f32x4){0.f,0.f,0.f,0.f}, 0, 0, 0);
                s0 = MFMA_BF16(a0, b2q[g], s0, 0, 0, 0);
                f32x4 s1 = MFMA_BF16(a1, b1q[g], (f32x4){0.f,0.f,0.f,0.f}, 0, 0, 0);
                s1 = MFMA_BF16(a1, b2q[g], s1, 0, 0, 0);
                union { __bf16 b[8]; bf16x8 v; } ap;
                ap.b[0] = (__bf16)__builtin_amdgcn_exp2f(s0[0]);
                ap.b[1] = (__bf16)__builtin_amdgcn_exp2f(s0[1]);
                ap.b[2] = (__bf16)__builtin_amdgcn_exp2f(s0[2]);
                ap.b[3] = (__bf16)__builtin_amdgcn_exp2f(s0[3]);
                ap.b[4] = (__bf16)__builtin_amdgcn_exp2f(s1[0]);
                ap.b[5] = (__bf16)__builtin_amdgcn_exp2f(s1[1]);
                ap.b[6] = (__bf16)__builtin_amdgcn_exp2f(s1[2]);
                ap.b[7] = (__bf16)__builtin_amdgcn_exp2f(s1[3]);
                lacc[g] = MFMA_BF16(ap.v, bones, lacc[g], 0, 0, 0);  // l += row-sum(P)
                og[g]   = MFMA_BF16(ap.v, vh, og[g], 0, 0, 0);
                og[g]   = MFMA_BF16(ap.v, vl, og[g], 0, 0, 0);
            }
        }
    }

    // ---- epilogue: l already in C-layout (same row mapping as og) ----
    #pragma unroll
    for (int g = 0; g < 2; ++g) {
        #pragma unroll
        for (int r = 0; r < 4; ++r) {
            const float val = og[g][r] * __builtin_amdgcn_rcpf(lacc[g][r]);
            const int row = q0 + wave * 32 + g * 16 + quad * 4 + r;
            const size_t off = ((size_t)row * T_STEPS + t) * 64 + hd * 16 + m;
            unsigned short hh = bf16_rne(val);
            obh[off] = hh;
            obl[off] = bf16_rne(val - bf16_tof(hh));
        }
    }
}

// ---------------------------------------------------------------------------
// Kernel 3: MFMA output projection (unchanged).
// ---------------------------------------------------------------------------
__global__ __launch_bounds__(256) void outproj_mfma_kernel(
    const unsigned short* __restrict__ obh, const unsigned short* __restrict__ obl,
    const float* __restrict__ Wo, const float* __restrict__ bo,
    float* __restrict__ out)
{
    __shared__ unsigned short woh[64 * WOS], wol[64 * WOS];
    __shared__ unsigned short oth[64 * OBS2], otl[64 * OBS2];
    __shared__ float sb[64];
    const int tid = threadIdx.x;

    #pragma unroll
    for (int i = 0; i < 16; ++i) {
        int idx = tid + 256 * i;
        int r = idx >> 6, c = idx & 63;
        float w = Wo[idx];
        unsigned short hh = bf16_rne(w);
        woh[r * WOS + c] = hh;
        wol[r * WOS + c] = bf16_rne(w - bf16_tof(hh));
    }
    if (tid < 64) sb[tid] = bo[tid];

    const size_t p0 = (size_t)blockIdx.x * 64;
    #pragma unroll
    for (int i = 0; i < 2; ++i) {
        int idx = tid + 256 * i;
        int r = idx >> 3, c = (idx & 7) * 8;
        *(uint4*)&oth[r * OBS2 + c] = *(const uint4*)(obh + (p0 + r) * 64 + c);
        *(uint4*)&otl[r * OBS2 + c] = *(const uint4*)(obl + (p0 + r) * 64 + c);
    }
    __syncthreads();

    const int wave = tid >> 6, lane = tid & 63;
    const int m = lane & 15, quad = lane >> 4;
    const int r0 = wave * 16;

    bf16x8 ah[2], al[2];
    #pragma unroll
    for (int kh = 0; kh < 2; ++kh) {
        ah[kh] = *(const bf16x8*)&oth[(r0 + m) * OBS2 + kh * 32 + quad * 8];
        al[kh] = *(const bf16x8*)&otl[(r0 + m) * OBS2 + kh * 32 + quad * 8];
    }

    f32x4 acc[4] = {{0,0,0,0},{0,0,0,0},{0,0,0,0},{0,0,0,0}};
    #pragma unroll
    for (int jt = 0; jt < 4; ++jt) {
        #pragma unroll
        for (int kh = 0; kh < 2; ++kh) {
            bf16x8 bh = *(const bf16x8*)&woh[(jt * 16 + m) * WOS + kh * 32 + quad * 8];
            bf16x8 bl = *(const bf16x8*)&wol[(jt * 16 + m) * WOS + kh * 32 + quad * 8];
            acc[jt] = MFMA_BF16(ah[kh], bh, acc[jt], 0, 0, 0);
            acc[jt] = MFMA_BF16(al[kh], bh, acc[jt], 0, 0, 0);
            acc[jt] = MFMA_BF16(ah[kh], bl, acc[jt], 0, 0, 0);
        }
    }

    #pragma unroll
    for (int jt = 0; jt < 4; ++jt) {
        const float b = sb[jt * 16 + m];
        #pragma unroll
        for (int r = 0; r < 4; ++r)
            out[(p0 + r0 + quad * 4 + r) * 64 + jt * 16 + m] = acc[jt][r] + b;
    }
}

// ---------------------------------------------------------------------------
extern "C" void kernel_launch(void* const* d_in, const int* in_sizes, int n_in,
                              void* d_out, int out_size, void* d_ws, size_t ws_size,
                              hipStream_t stream)
{
    (void)in_sizes; (void)n_in; (void)out_size; (void)ws_size;
    const float* values = (const float*)d_in[0];
    const float* keys   = (const float*)d_in[1];
    const float* query  = (const float*)d_in[2];
    const float* Wv     = (const float*)d_in[3];
    const float* Wk     = (const float*)d_in[4];
    const float* Wq     = (const float*)d_in[5];
    const float* Wo     = (const float*)d_in[6];
    const float* bo     = (const float*)d_in[7];

    const size_t TOT = (size_t)144 * N_NODES * 16;   // 2,359,296 bf16 per plane
    unsigned short* ws16 = (unsigned short*)d_ws;
    unsigned short* qhi  = ws16;
    unsigned short* qlo  = ws16 + 1*TOT;
    unsigned short* khi  = ws16 + 2*TOT;
    unsigned short* klo  = ws16 + 3*TOT;
    unsigned short* vthi = ws16 + 4*TOT;
    unsigned short* vtlo = ws16 + 5*TOT;
    unsigned short* obh  = ws16 + 6*TOT;
    unsigned short* obl  = ws16 + 7*TOT;             // total ws = 8*TOT*2B = 37.75 MB

    proj6_kernel<<<dim3(288, 3), 128, 0, stream>>>(values, keys, query, Wv, Wk, Wq,
                                                   qhi, qlo, khi, klo, vthi, vtlo);
    attn_mfma5_kernel<<<dim3(16 * 144), 128, 0, stream>>>(qhi, qlo, khi, klo, vthi, vtlo,
                                                          obh, obl);
    outproj_mfma_kernel<<<dim3(576), 256, 0, stream>>>(obh, obl, Wo, bo, (float*)d_out);
}